// Round 7
// baseline (395.681 us; speedup 1.0000x reference)
//
#include <hip/hip_runtime.h>
#include <math.h>

#define N_NODES 25000
#define E_EDGES 250000
#define HID 128
#define OUTC 64
#define NPB 98          // ceil(25000/256)

using bf16x8 = __attribute__((ext_vector_type(8))) short;
using u16x8  = __attribute__((ext_vector_type(8))) unsigned short;
using f32x4  = __attribute__((ext_vector_type(4))) float;

__device__ __forceinline__ unsigned short f2bf(float f) {   // RNE float->bf16
    unsigned u = __float_as_uint(f);
    u = (u + 0x7fffu + ((u >> 16) & 1u)) >> 16;
    return (unsigned short)u;
}
__device__ __forceinline__ float bf2f(unsigned short h) {
    return __uint_as_float(((unsigned)h) << 16);
}
__device__ __forceinline__ float gelu_f(float x) {
    return 0.5f * x * (1.0f + erff(x * 0.70710678118654752440f));
}

// ============================ CSR build ============================
__global__ void hist2(const int* __restrict__ e0, const int* __restrict__ e1,
                      int* __restrict__ cnt) {
    int r = blockIdx.y;
    const int* d = (r ? e1 : e0) + E_EDGES;
    int e = blockIdx.x * 256 + threadIdx.x;
    if (e < E_EDGES) atomicAdd(&cnt[r * N_NODES + d[e]], 1);
}

__global__ void csr_partial(const int* __restrict__ cnt, int* __restrict__ part) {
    int r = blockIdx.y, b = blockIdx.x, t = threadIdx.x;
    int idx = b * 256 + t;
    int v = (idx < N_NODES) ? cnt[r * N_NODES + idx] : 0;
    #pragma unroll
    for (int d = 1; d < 64; d <<= 1) v += __shfl_xor(v, d);
    __shared__ int ws[4];
    if ((t & 63) == 0) ws[t >> 6] = v;
    __syncthreads();
    if (t == 0) part[r * NPB + b] = ws[0] + ws[1] + ws[2] + ws[3];
}

__global__ void csr_scanpart(int* __restrict__ part) {
    int w = threadIdx.x >> 6, lane = threadIdx.x & 63;
    int base = w * NPB;
    int a = part[base + lane];
    int b = (lane < NPB - 64) ? part[base + 64 + lane] : 0;
    int va = a, vb = b;
    #pragma unroll
    for (int d = 1; d < 64; d <<= 1) { int u = __shfl_up(va, d); if (lane >= d) va += u; }
    #pragma unroll
    for (int d = 1; d < 64; d <<= 1) { int u = __shfl_up(vb, d); if (lane >= d) vb += u; }
    int tot0 = __shfl(va, 63);
    part[base + lane] = va - a;
    if (lane < NPB - 64) part[base + 64 + lane] = vb - b + tot0;
}

__global__ void csr_write(int* __restrict__ cnt, const int* __restrict__ part,
                          int* __restrict__ rowptr) {
    int r = blockIdx.y, b = blockIdx.x, t = threadIdx.x;
    int idx = b * 256 + t;
    int v = (idx < N_NODES) ? cnt[r * N_NODES + idx] : 0;
    int lane = t & 63, w = t >> 6;
    int iv = v;
    #pragma unroll
    for (int d = 1; d < 64; d <<= 1) { int u = __shfl_up(iv, d); if (lane >= d) iv += u; }
    __shared__ int wtot[4];
    if (lane == 63) wtot[w] = iv;
    __syncthreads();
    int woff = part[r * NPB + b];
    #pragma unroll
    for (int i = 0; i < 4; i++) if (i < w) woff += wtot[i];
    int excl = woff + iv - v;
    if (idx < N_NODES) {
        rowptr[r * (N_NODES + 1) + idx] = excl;
        cnt[r * N_NODES + idx] = excl;
    }
    if (b == 0 && t == 0) rowptr[r * (N_NODES + 1) + N_NODES] = E_EDGES;
}

__global__ void scatter2(const int* __restrict__ e0, const int* __restrict__ e1,
                         int* __restrict__ cursor, int* __restrict__ srcs) {
    int r = blockIdx.y;
    const int* e = r ? e1 : e0;
    int i = blockIdx.x * 256 + threadIdx.x;
    if (i < E_EDGES) {
        int p = atomicAdd(&cursor[r * N_NODES + e[E_EDGES + i]], 1);
        srcs[r * E_EDGES + p] = e[i];
    }
}

// =============== weight prep: transpose fp32 [128][C] -> bf16 [C][128] ===============
__global__ void tconv(const float* __restrict__ src, unsigned short* __restrict__ dst, int C) {
    int m = blockIdx.y;
    int idx = blockIdx.x * 256 + threadIdx.x;
    if (idx >= C * 128) return;
    int c = idx >> 7, k = idx & 127;
    dst[(size_t)m * C * 128 + idx] = f2bf(src[(size_t)m * 128 * C + k * C + c]);
}

// fused QKV' weights, transposed bf16 [p][384col][128k] + fp32 bias [p][384]
__global__ __launch_bounds__(256) void prep_qkv(
    const float* __restrict__ Wq, const float* __restrict__ bq,
    const float* __restrict__ Wk, const float* __restrict__ bk,
    const float* __restrict__ Wv, const float* __restrict__ bv,
    const float* __restrict__ a_rel, const float* __restrict__ m_rel,
    unsigned short* __restrict__ WT, float* __restrict__ bfq)
{
    int p = blockIdx.y;                    // l*2+t (relation r == source type t)
    __shared__ float sA[2048], sM[2048];
    for (int i = threadIdx.x; i < 2048; i += 256) {
        sA[i] = a_rel[p * 2048 + i];
        sM[i] = m_rel[p * 2048 + i];
    }
    __syncthreads();
    int idx = blockIdx.x * 256 + threadIdx.x;
    if (idx >= 384 * 129) return;
    int c = idx / 129;
    int ik = idx - c * 129;                // 0..127 weight row, 128 = bias
    const float* wq = Wq + (size_t)p * 16384;
    const float* wk = Wk + (size_t)p * 16384;
    const float* wv = Wv + (size_t)p * 16384;
    float val;
    if (c < 128) {
        val = (ik < 128) ? wq[ik * 128 + c] : bq[p * 128 + c];
    } else if (c < 256) {
        int cc = c - 128, h = cc >> 4, f = cc & 15;
        const float* row = (ik < 128) ? &wk[ik * 128 + h * 16] : &bk[p * 128 + h * 16];
        float s = 0.f;
        #pragma unroll
        for (int d = 0; d < 16; d++) s = fmaf(row[d], sA[h * 256 + d * 16 + f], s);
        val = s;
    } else {
        int cc = c - 256, h = cc >> 4, f = cc & 15;
        const float* row = (ik < 128) ? &wv[ik * 128 + h * 16] : &bv[p * 128 + h * 16];
        float s = 0.f;
        #pragma unroll
        for (int d = 0; d < 16; d++) s = fmaf(row[d], sM[h * 256 + d * 16 + f], s);
        val = s;
    }
    if (ik < 128) WT[(size_t)p * 384 * 128 + (size_t)c * 128 + ik] = f2bf(val);
    else bfq[p * 384 + c] = val;
}

// ============================ MFMA matmul (LDS-staged W) ============================
// C[z] = epilogue(A[z][nrows,128] @ WT[z]^T + b[z]);  WT bf16 [NOUT][128].
// KVIL: remap cols >=128 to interleaved [k4|v4] groups for the attention gather.
// OUTMODE: 0 bf16 store, 1 relu+bf16, 2 gated residual bf16 (in-place), 3 fp32 store.
template<int NOUT, int BN, int OUTMODE, int A_FP32, int KVIL>
__global__ __launch_bounds__(256) void mm4_kernel(
    const void* __restrict__ A0, const void* __restrict__ A1,
    const unsigned short* __restrict__ W0, const unsigned short* __restrict__ W1,
    const float* __restrict__ b0, const float* __restrict__ b1,
    const unsigned short* __restrict__ res0, const unsigned short* __restrict__ res1,
    const float* __restrict__ skipp,
    void* __restrict__ C0, void* __restrict__ C1, int nrows)
{
    constexpr int CF = BN / 16;
    __shared__ unsigned short sW[BN * 128];
    int z = blockIdx.z;
    const void* Av = z ? A1 : A0;
    const unsigned short* W = z ? W1 : W0;
    const float* bias = z ? b1 : b0;
    const unsigned short* res = z ? res1 : res0;
    void* Cv = z ? C1 : C0;

    int t = threadIdx.x;
    int w = t >> 6, lane = t & 63, lo = lane & 15, hi = lane >> 4;
    int col0 = blockIdx.y * BN;
    int rowbase = blockIdx.x * 128 + w * 32;

    // ---- stage swizzled W tile: sW[col*128 + (ch^(col&7))*8] = Wg[col*128 + ch*8]
    const unsigned short* Wg = W + (size_t)col0 * 128;
    #pragma unroll
    for (int it = 0; it < BN / 16; ++it) {            // BN*16 chunks / 256 threads
        int idx = it * 256 + t;
        int col = idx >> 4, ch = idx & 15;
        bf16x8 v = *(const bf16x8*)(Wg + (size_t)col * 128 + ch * 8);
        *(bf16x8*)&sW[col * 128 + ((ch ^ (col & 7)) << 3)] = v;
    }

    // ---- A fragments (2 row-frags x 4 k-frags), loads overlap the staging
    bf16x8 a[2][4];
    #pragma unroll
    for (int rf = 0; rf < 2; rf++) {
        int r = rowbase + rf * 16 + lo;
        if (r > nrows - 1) r = nrows - 1;
        if (A_FP32) {
            const float* Arow = (const float*)Av + (size_t)r * HID;
            #pragma unroll
            for (int kk = 0; kk < 4; kk++) {
                float4 x0 = *(const float4*)(Arow + kk * 32 + hi * 8);
                float4 x1 = *(const float4*)(Arow + kk * 32 + hi * 8 + 4);
                bf16x8 v;
                v[0] = (short)f2bf(x0.x); v[1] = (short)f2bf(x0.y);
                v[2] = (short)f2bf(x0.z); v[3] = (short)f2bf(x0.w);
                v[4] = (short)f2bf(x1.x); v[5] = (short)f2bf(x1.y);
                v[6] = (short)f2bf(x1.z); v[7] = (short)f2bf(x1.w);
                a[rf][kk] = v;
            }
        } else {
            const unsigned short* Arow = (const unsigned short*)Av + (size_t)r * HID;
            #pragma unroll
            for (int kk = 0; kk < 4; kk++)
                a[rf][kk] = *(const bf16x8*)(Arow + kk * 32 + hi * 8);
        }
    }
    __syncthreads();

    f32x4 acc[2][CF];
    #pragma unroll
    for (int rf = 0; rf < 2; rf++)
        #pragma unroll
        for (int cf = 0; cf < CF; cf++) acc[rf][cf] = (f32x4){0.f, 0.f, 0.f, 0.f};

    #pragma unroll
    for (int cf = 0; cf < CF; cf++) {
        int colb = cf * 16 + lo;
        int sbase = colb * 128;
        int sx = colb & 7;
        bf16x8 bfr[4];
        #pragma unroll
        for (int kk = 0; kk < 4; kk++) {
            int ch = kk * 4 + hi;
            bfr[kk] = *(const bf16x8*)&sW[sbase + ((ch ^ sx) << 3)];
        }
        #pragma unroll
        for (int kk = 0; kk < 4; kk++) {
            acc[0][cf] = __builtin_amdgcn_mfma_f32_16x16x32_bf16(a[0][kk], bfr[kk], acc[0][cf], 0, 0, 0);
            acc[1][cf] = __builtin_amdgcn_mfma_f32_16x16x32_bf16(a[1][kk], bfr[kk], acc[1][cf], 0, 0, 0);
        }
    }

    float beta = 0.f, omb = 0.f;
    if (OUTMODE == 2) { float sv = skipp[z]; beta = 1.f / (1.f + __expf(-sv)); omb = 1.f - beta; }
    #pragma unroll
    for (int rf = 0; rf < 2; rf++) {
        #pragma unroll
        for (int cf = 0; cf < CF; cf++) {
            int col = col0 + cf * 16 + lo;
            float bb = bias[col];
            int scol = col;
            if (KVIL) {
                if (col >= 256)      { int cc = col - 256; scol = 128 + ((cc >> 2) << 3) + 4 + (cc & 3); }
                else if (col >= 128) { int cc = col - 128; scol = 128 + ((cc >> 2) << 3) + (cc & 3); }
            }
            #pragma unroll
            for (int j = 0; j < 4; j++) {
                int r = rowbase + rf * 16 + hi * 4 + j;
                if (r >= nrows) continue;
                float v = acc[rf][cf][j] + bb;
                if (OUTMODE == 1) v = fmaxf(v, 0.f);
                if (OUTMODE == 2) v = beta * v + omb * bf2f(res[(size_t)r * NOUT + col]);
                if (OUTMODE == 3) ((float*)Cv)[(size_t)r * NOUT + col] = v;
                else ((unsigned short*)Cv)[(size_t)r * NOUT + scol] = f2bf(v);
            }
        }
    }
}

// ==================== attention: one wave per dst node, edge-split halves ====================
// Lanes 0-31 process even edges, 32-63 odd edges of the SAME node (no loop divergence);
// the two online-softmax states merge exactly at the end via shfl_xor(...,32).
// KV interleaved layout: one 16B load per edge per lane. gelu fused in epilogue.
__global__ __launch_bounds__(256) void attn4_kernel(
    const unsigned short* __restrict__ qkv0, const unsigned short* __restrict__ qkv1,
    const int* __restrict__ rowptr, const int* __restrict__ srcs,
    const float* __restrict__ prel,
    unsigned short* __restrict__ agg0, unsigned short* __restrict__ agg1, int n)
{
    int r = blockIdx.y;                    // relation; src type = r, dst type = 1-r
    const unsigned short* qd = r ? qkv0 : qkv1;
    const unsigned short* sv = r ? qkv1 : qkv0;
    unsigned short* agg      = r ? agg0 : agg1;
    const int* rp = rowptr + r * (N_NODES + 1);
    const int* ss = srcs + r * E_EDGES;

    int nid = blockIdx.x * 4 + (threadIdx.x >> 6);
    if (nid >= n) return;
    int lane = threadIdx.x & 63;
    int half = lane >> 5;                  // which edge parity this half-wave owns
    int g = lane & 31;                     // channel group: 4 channels
    int c0 = g << 2;
    int h = g >> 2;

    const unsigned short* qrow = qd + (size_t)nid * 384 + c0;
    float q0 = bf2f(qrow[0]), q1 = bf2f(qrow[1]), q2 = bf2f(qrow[2]), q3 = bf2f(qrow[3]);
    float p = prel[r * 8 + h] * 0.25f;

    float m = -1e30f, ssum = 0.f;          // -1e30 (not -inf): merge stays NaN-free
    float ax = 0.f, ay = 0.f, az = 0.f, aw = 0.f;
    int beg = rp[nid], end = rp[nid + 1];
    int i0 = beg + half;
    if (i0 < end) {
        u16x8 kv = *(const u16x8*)(sv + (size_t)ss[i0] * 384 + 128 + (g << 3));
        for (int i = i0; i < end; i += 2) {
            int nx = i + 2 < end ? i + 2 : i;
            u16x8 kvn = *(const u16x8*)(sv + (size_t)ss[nx] * 384 + 128 + (g << 3));
            float sc = q0 * bf2f(kv[0]) + q1 * bf2f(kv[1]) + q2 * bf2f(kv[2]) + q3 * bf2f(kv[3]);
            sc += __shfl_xor(sc, 1);
            sc += __shfl_xor(sc, 2);
            float score = sc * p;
            float nm = fmaxf(m, score);
            float resc = __expf(m - nm);
            float e = __expf(score - nm);
            ssum = ssum * resc + e;
            ax = ax * resc + e * bf2f(kv[4]);
            ay = ay * resc + e * bf2f(kv[5]);
            az = az * resc + e * bf2f(kv[6]);
            aw = aw * resc + e * bf2f(kv[7]);
            m = nm;
            kv = kvn;
        }
    }
    // ---- merge the two halves' online-softmax states
    float mo = __shfl_xor(m, 32);
    float nm2 = fmaxf(m, mo);
    float f = __expf(m - nm2);
    ssum *= f; ax *= f; ay *= f; az *= f; aw *= f;
    ssum += __shfl_xor(ssum, 32);
    ax += __shfl_xor(ax, 32);
    ay += __shfl_xor(ay, 32);
    az += __shfl_xor(az, 32);
    aw += __shfl_xor(aw, 32);

    if (half == 0) {
        float inv = 1.f / (ssum + 1e-16f);
        ushort4 o;
        o.x = f2bf(gelu_f(ax * inv)); o.y = f2bf(gelu_f(ay * inv));
        o.z = f2bf(gelu_f(az * inv)); o.w = f2bf(gelu_f(aw * inv));
        *(ushort4*)(agg + (size_t)nid * HID + c0) = o;
    }
}

// ============================ orchestration ============================
extern "C" void kernel_launch(void* const* d_in, const int* in_sizes, int n_in,
                              void* d_out, int out_size, void* d_ws, size_t ws_size,
                              hipStream_t stream)
{
    (void)in_sizes; (void)n_in; (void)out_size; (void)ws_size;
    const float* x_author = (const float*)d_in[0];
    const float* x_paper  = (const float*)d_in[1];
    const int*   e_writes = (const int*)d_in[2];
    const int*   e_rev    = (const int*)d_in[3];
    const float* W_in = (const float*)d_in[4];
    const float* b_in = (const float*)d_in[5];
    const float* Wq = (const float*)d_in[6];
    const float* bq = (const float*)d_in[7];
    const float* Wk = (const float*)d_in[8];
    const float* bk = (const float*)d_in[9];
    const float* Wv = (const float*)d_in[10];
    const float* bv = (const float*)d_in[11];
    const float* Wa = (const float*)d_in[12];
    const float* ba = (const float*)d_in[13];
    const float* skip = (const float*)d_in[14];
    const float* a_rel = (const float*)d_in[15];
    const float* m_rel = (const float*)d_in[16];
    const float* p_rel = (const float*)d_in[17];
    const float* W_out = (const float*)d_in[18];
    const float* b_out = (const float*)d_in[19];
    float* out = (float*)d_out;

    const size_t NC = (size_t)N_NODES * HID;       // 3.2M elems
    const size_t NQ = (size_t)N_NODES * 384;
    unsigned short* U = (unsigned short*)d_ws;
    unsigned short* cur0 = U;             unsigned short* cur1 = U + NC;
    unsigned short* agg0 = U + 2 * NC;    unsigned short* agg1 = U + 3 * NC;
    unsigned short* qkv0 = U + 4 * NC;    unsigned short* qkv1 = U + 4 * NC + NQ;
    unsigned short* WTin  = U + 4 * NC + 2 * NQ;            // 2*128*128
    unsigned short* WTqkv = WTin + 2 * 16384;               // 4*384*128
    unsigned short* WTa   = WTqkv + 4 * 49152;              // 4*128*128
    unsigned short* WTout = WTa + 4 * 16384;                // 64*128
    float* bfq = (float*)(WTout + OUTC * 128);              // 4*384 fp32
    int* I      = (int*)(bfq + 4 * 384);
    int* cnt    = I;
    int* part   = I + 2 * N_NODES;
    int* rowptr = part + 2 * NPB;
    int* srcs   = rowptr + 2 * (N_NODES + 1);

    dim3 blk(256);
    int eGrid = (E_EDGES + 255) / 256;
    int mmX = (N_NODES + 127) / 128;                        // 196
    int attnX = (N_NODES + 3) / 4;                          // 6250 (1 wave per node)
    int prepX = (384 * 129 + 255) / 256;                    // 194

    // ---- CSR ----
    hipMemsetAsync(cnt, 0, 2 * N_NODES * sizeof(int), stream);
    hist2<<<dim3(eGrid, 2), blk, 0, stream>>>(e_writes, e_rev, cnt);
    csr_partial<<<dim3(NPB, 2), blk, 0, stream>>>(cnt, part);
    csr_scanpart<<<1, 128, 0, stream>>>(part);
    csr_write<<<dim3(NPB, 2), blk, 0, stream>>>(cnt, part, rowptr);
    scatter2<<<dim3(eGrid, 2), blk, 0, stream>>>(e_writes, e_rev, cnt, srcs);

    // ---- weight prep ----
    tconv<<<dim3(64, 2), blk, 0, stream>>>(W_in, WTin, HID);
    tconv<<<dim3(64, 4), blk, 0, stream>>>(Wa, WTa, HID);
    tconv<<<dim3(32, 1), blk, 0, stream>>>(W_out, WTout, OUTC);
    prep_qkv<<<dim3(prepX, 4), blk, 0, stream>>>(Wq, bq, Wk, bk, Wv, bv, a_rel, m_rel, WTqkv, bfq);

    // ---- input projection + relu (fp32 A) ----
    mm4_kernel<HID, 128, 1, 1, 0><<<dim3(mmX, 1, 2), blk, 0, stream>>>(
        x_author, x_paper, WTin, WTin + 16384, b_in, b_in + HID,
        nullptr, nullptr, nullptr, cur0, cur1, N_NODES);

    for (int l = 0; l < 2; l++) {
        mm4_kernel<384, 128, 0, 0, 1><<<dim3(mmX, 3, 2), blk, 0, stream>>>(
            cur0, cur1,
            WTqkv + (size_t)(l * 2 + 0) * 49152, WTqkv + (size_t)(l * 2 + 1) * 49152,
            bfq + (l * 2 + 0) * 384, bfq + (l * 2 + 1) * 384,
            nullptr, nullptr, nullptr, qkv0, qkv1, N_NODES);
        attn4_kernel<<<dim3(attnX, 2), blk, 0, stream>>>(
            qkv0, qkv1, rowptr, srcs, p_rel + (size_t)l * 16, agg0, agg1, N_NODES);
        mm4_kernel<HID, 128, 2, 0, 0><<<dim3(mmX, 1, 2), blk, 0, stream>>>(
            agg0, agg1,
            WTa + (size_t)(l * 2 + 0) * 16384, WTa + (size_t)(l * 2 + 1) * 16384,
            ba + (l * 2 + 0) * HID, ba + (l * 2 + 1) * HID,
            cur0, cur1, skip + l * 2, cur0, cur1, N_NODES);
    }

    // ---- final projection (fp32 out) ----
    mm4_kernel<OUTC, 64, 3, 0, 0><<<dim3(mmX, 1, 2), blk, 0, stream>>>(
        cur0, cur1, WTout, WTout, b_out, b_out,
        nullptr, nullptr, nullptr, out, out + (size_t)N_NODES * OUTC, N_NODES);
}

// Round 10
// 372.137 us; speedup vs baseline: 1.0633x; 1.0633x over previous
//
#include <hip/hip_runtime.h>
#include <math.h>

#define N_NODES 25000
#define E_EDGES 250000
#define HID 128
#define OUTC 64
#define NPB 98          // ceil(25000/256)

using bf16x8 = __attribute__((ext_vector_type(8))) short;
using u16x8  = __attribute__((ext_vector_type(8))) unsigned short;
using f32x4  = __attribute__((ext_vector_type(4))) float;

__device__ __forceinline__ unsigned short f2bf(float f) {   // RNE float->bf16
    unsigned u = __float_as_uint(f);
    u = (u + 0x7fffu + ((u >> 16) & 1u)) >> 16;
    return (unsigned short)u;
}
__device__ __forceinline__ float bf2f(unsigned short h) {
    return __uint_as_float(((unsigned)h) << 16);
}
__device__ __forceinline__ float gelu_f(float x) {
    return 0.5f * x * (1.0f + erff(x * 0.70710678118654752440f));
}

// ============================ CSR build ============================
__global__ void hist2(const int* __restrict__ e0, const int* __restrict__ e1,
                      int* __restrict__ cnt) {
    int r = blockIdx.y;
    const int* d = (r ? e1 : e0) + E_EDGES;
    int e = blockIdx.x * 256 + threadIdx.x;
    if (e < E_EDGES) atomicAdd(&cnt[r * N_NODES + d[e]], 1);
}

__global__ void csr_partial(const int* __restrict__ cnt, int* __restrict__ part) {
    int r = blockIdx.y, b = blockIdx.x, t = threadIdx.x;
    int idx = b * 256 + t;
    int v = (idx < N_NODES) ? cnt[r * N_NODES + idx] : 0;
    #pragma unroll
    for (int d = 1; d < 64; d <<= 1) v += __shfl_xor(v, d);
    __shared__ int ws[4];
    if ((t & 63) == 0) ws[t >> 6] = v;
    __syncthreads();
    if (t == 0) part[r * NPB + b] = ws[0] + ws[1] + ws[2] + ws[3];
}

__global__ void csr_scanpart(int* __restrict__ part) {
    int w = threadIdx.x >> 6, lane = threadIdx.x & 63;
    int base = w * NPB;
    int a = part[base + lane];
    int b = (lane < NPB - 64) ? part[base + 64 + lane] : 0;
    int va = a, vb = b;
    #pragma unroll
    for (int d = 1; d < 64; d <<= 1) { int u = __shfl_up(va, d); if (lane >= d) va += u; }
    #pragma unroll
    for (int d = 1; d < 64; d <<= 1) { int u = __shfl_up(vb, d); if (lane >= d) vb += u; }
    int tot0 = __shfl(va, 63);
    part[base + lane] = va - a;
    if (lane < NPB - 64) part[base + 64 + lane] = vb - b + tot0;
}

__global__ void csr_write(int* __restrict__ cnt, const int* __restrict__ part,
                          int* __restrict__ rowptr) {
    int r = blockIdx.y, b = blockIdx.x, t = threadIdx.x;
    int idx = b * 256 + t;
    int v = (idx < N_NODES) ? cnt[r * N_NODES + idx] : 0;
    int lane = t & 63, w = t >> 6;
    int iv = v;
    #pragma unroll
    for (int d = 1; d < 64; d <<= 1) { int u = __shfl_up(iv, d); if (lane >= d) iv += u; }
    __shared__ int wtot[4];
    if (lane == 63) wtot[w] = iv;
    __syncthreads();
    int woff = part[r * NPB + b];
    #pragma unroll
    for (int i = 0; i < 4; i++) if (i < w) woff += wtot[i];
    int excl = woff + iv - v;
    if (idx < N_NODES) {
        rowptr[r * (N_NODES + 1) + idx] = excl;
        cnt[r * N_NODES + idx] = excl;
    }
    if (b == 0 && t == 0) rowptr[r * (N_NODES + 1) + N_NODES] = E_EDGES;
}

__global__ void scatter2(const int* __restrict__ e0, const int* __restrict__ e1,
                         int* __restrict__ cursor, int* __restrict__ srcs) {
    int r = blockIdx.y;
    const int* e = r ? e1 : e0;
    int i = blockIdx.x * 256 + threadIdx.x;
    if (i < E_EDGES) {
        int p = atomicAdd(&cursor[r * N_NODES + e[E_EDGES + i]], 1);
        srcs[r * E_EDGES + p] = e[i];
    }
}

// =============== weight prep: transpose fp32 [128][C] -> bf16 [C][128] ===============
__global__ void tconv(const float* __restrict__ src, unsigned short* __restrict__ dst, int C) {
    int m = blockIdx.y;
    int idx = blockIdx.x * 256 + threadIdx.x;
    if (idx >= C * 128) return;
    int c = idx >> 7, k = idx & 127;
    dst[(size_t)m * C * 128 + idx] = f2bf(src[(size_t)m * 128 * C + k * C + c]);
}

// fused QKV' weights, transposed bf16 [p][384col][128k] + fp32 bias [p][384]
__global__ __launch_bounds__(256) void prep_qkv(
    const float* __restrict__ Wq, const float* __restrict__ bq,
    const float* __restrict__ Wk, const float* __restrict__ bk,
    const float* __restrict__ Wv, const float* __restrict__ bv,
    const float* __restrict__ a_rel, const float* __restrict__ m_rel,
    unsigned short* __restrict__ WT, float* __restrict__ bfq)
{
    int p = blockIdx.y;                    // l*2+t (relation r == source type t)
    __shared__ float sA[2048], sM[2048];
    for (int i = threadIdx.x; i < 2048; i += 256) {
        sA[i] = a_rel[p * 2048 + i];
        sM[i] = m_rel[p * 2048 + i];
    }
    __syncthreads();
    int idx = blockIdx.x * 256 + threadIdx.x;
    if (idx >= 384 * 129) return;
    int c = idx / 129;
    int ik = idx - c * 129;                // 0..127 weight row, 128 = bias
    const float* wq = Wq + (size_t)p * 16384;
    const float* wk = Wk + (size_t)p * 16384;
    const float* wv = Wv + (size_t)p * 16384;
    float val;
    if (c < 128) {
        val = (ik < 128) ? wq[ik * 128 + c] : bq[p * 128 + c];
    } else if (c < 256) {
        int cc = c - 128, h = cc >> 4, f = cc & 15;
        const float* row = (ik < 128) ? &wk[ik * 128 + h * 16] : &bk[p * 128 + h * 16];
        float s = 0.f;
        #pragma unroll
        for (int d = 0; d < 16; d++) s = fmaf(row[d], sA[h * 256 + d * 16 + f], s);
        val = s;
    } else {
        int cc = c - 256, h = cc >> 4, f = cc & 15;
        const float* row = (ik < 128) ? &wv[ik * 128 + h * 16] : &bv[p * 128 + h * 16];
        float s = 0.f;
        #pragma unroll
        for (int d = 0; d < 16; d++) s = fmaf(row[d], sM[h * 256 + d * 16 + f], s);
        val = s;
    }
    if (ik < 128) WT[(size_t)p * 384 * 128 + (size_t)c * 128 + ik] = f2bf(val);
    else bfq[p * 384 + c] = val;
}

// ============================ MFMA matmul (LDS-staged W) ============================
// C[z] = epilogue(A[z][nrows,128] @ WT[z]^T + b[z]);  WT bf16 [NOUT][128].
// KVIL: remap cols >=128 to interleaved [k4|v4] groups for the attention gather.
// OUTMODE: 0 bf16 store, 1 relu+bf16, 2 gated residual bf16 (in-place), 3 fp32 store.
template<int NOUT, int BN, int OUTMODE, int A_FP32, int KVIL>
__global__ __launch_bounds__(256) void mm4_kernel(
    const void* __restrict__ A0, const void* __restrict__ A1,
    const unsigned short* __restrict__ W0, const unsigned short* __restrict__ W1,
    const float* __restrict__ b0, const float* __restrict__ b1,
    const unsigned short* __restrict__ res0, const unsigned short* __restrict__ res1,
    const float* __restrict__ skipp,
    void* __restrict__ C0, void* __restrict__ C1, int nrows)
{
    constexpr int CF = BN / 16;
    __shared__ unsigned short sW[BN * 128];
    int z = blockIdx.z;
    const void* Av = z ? A1 : A0;
    const unsigned short* W = z ? W1 : W0;
    const float* bias = z ? b1 : b0;
    const unsigned short* res = z ? res1 : res0;
    void* Cv = z ? C1 : C0;

    int t = threadIdx.x;
    int w = t >> 6, lane = t & 63, lo = lane & 15, hi = lane >> 4;
    int col0 = blockIdx.y * BN;
    int rowbase = blockIdx.x * 128 + w * 32;

    // ---- stage swizzled W tile: sW[col*128 + (ch^(col&7))*8] = Wg[col*128 + ch*8]
    const unsigned short* Wg = W + (size_t)col0 * 128;
    #pragma unroll
    for (int it = 0; it < BN / 16; ++it) {            // BN*16 chunks / 256 threads
        int idx = it * 256 + t;
        int col = idx >> 4, ch = idx & 15;
        bf16x8 v = *(const bf16x8*)(Wg + (size_t)col * 128 + ch * 8);
        *(bf16x8*)&sW[col * 128 + ((ch ^ (col & 7)) << 3)] = v;
    }

    // ---- A fragments (2 row-frags x 4 k-frags), loads overlap the staging
    bf16x8 a[2][4];
    #pragma unroll
    for (int rf = 0; rf < 2; rf++) {
        int r = rowbase + rf * 16 + lo;
        if (r > nrows - 1) r = nrows - 1;
        if (A_FP32) {
            const float* Arow = (const float*)Av + (size_t)r * HID;
            #pragma unroll
            for (int kk = 0; kk < 4; kk++) {
                float4 x0 = *(const float4*)(Arow + kk * 32 + hi * 8);
                float4 x1 = *(const float4*)(Arow + kk * 32 + hi * 8 + 4);
                bf16x8 v;
                v[0] = (short)f2bf(x0.x); v[1] = (short)f2bf(x0.y);
                v[2] = (short)f2bf(x0.z); v[3] = (short)f2bf(x0.w);
                v[4] = (short)f2bf(x1.x); v[5] = (short)f2bf(x1.y);
                v[6] = (short)f2bf(x1.z); v[7] = (short)f2bf(x1.w);
                a[rf][kk] = v;
            }
        } else {
            const unsigned short* Arow = (const unsigned short*)Av + (size_t)r * HID;
            #pragma unroll
            for (int kk = 0; kk < 4; kk++)
                a[rf][kk] = *(const bf16x8*)(Arow + kk * 32 + hi * 8);
        }
    }
    __syncthreads();

    f32x4 acc[2][CF];
    #pragma unroll
    for (int rf = 0; rf < 2; rf++)
        #pragma unroll
        for (int cf = 0; cf < CF; cf++) acc[rf][cf] = (f32x4){0.f, 0.f, 0.f, 0.f};

    #pragma unroll
    for (int cf = 0; cf < CF; cf++) {
        int colb = cf * 16 + lo;
        int sbase = colb * 128;
        int sx = colb & 7;
        bf16x8 bfr[4];
        #pragma unroll
        for (int kk = 0; kk < 4; kk++) {
            int ch = kk * 4 + hi;
            bfr[kk] = *(const bf16x8*)&sW[sbase + ((ch ^ sx) << 3)];
        }
        #pragma unroll
        for (int kk = 0; kk < 4; kk++) {
            acc[0][cf] = __builtin_amdgcn_mfma_f32_16x16x32_bf16(a[0][kk], bfr[kk], acc[0][cf], 0, 0, 0);
            acc[1][cf] = __builtin_amdgcn_mfma_f32_16x16x32_bf16(a[1][kk], bfr[kk], acc[1][cf], 0, 0, 0);
        }
    }

    float beta = 0.f, omb = 0.f;
    if (OUTMODE == 2) { float sv = skipp[z]; beta = 1.f / (1.f + __expf(-sv)); omb = 1.f - beta; }
    #pragma unroll
    for (int rf = 0; rf < 2; rf++) {
        #pragma unroll
        for (int cf = 0; cf < CF; cf++) {
            int col = col0 + cf * 16 + lo;
            float bb = bias[col];
            int scol = col;
            if (KVIL) {
                if (col >= 256)      { int cc = col - 256; scol = 128 + ((cc >> 2) << 3) + 4 + (cc & 3); }
                else if (col >= 128) { int cc = col - 128; scol = 128 + ((cc >> 2) << 3) + (cc & 3); }
            }
            #pragma unroll
            for (int j = 0; j < 4; j++) {
                int r = rowbase + rf * 16 + hi * 4 + j;
                if (r >= nrows) continue;
                float v = acc[rf][cf][j] + bb;
                if (OUTMODE == 1) v = fmaxf(v, 0.f);
                if (OUTMODE == 2) v = beta * v + omb * bf2f(res[(size_t)r * NOUT + col]);
                if (OUTMODE == 3) ((float*)Cv)[(size_t)r * NOUT + col] = v;
                else ((unsigned short*)Cv)[(size_t)r * NOUT + scol] = f2bf(v);
            }
        }
    }
}

// ==================== attention: one wave per node, 4 edge streams, 2-deep pipeline ====================
// Half-waves take edge parities; each half runs TWO interleaved streams (stride 4) with
// independent online-softmax states -> 4 gathers in flight/wave, chain length deg/4.
// Indices for iter i+8 load while gathers for i+4 issue (index->gather decoupled).
__global__ __launch_bounds__(256) void attn5_kernel(
    const unsigned short* __restrict__ qkv0, const unsigned short* __restrict__ qkv1,
    const int* __restrict__ rowptr, const int* __restrict__ srcs,
    const float* __restrict__ prel,
    unsigned short* __restrict__ agg0, unsigned short* __restrict__ agg1, int n)
{
    int r = blockIdx.y;                    // relation; src type = r, dst type = 1-r
    const unsigned short* qd = r ? qkv0 : qkv1;
    const unsigned short* sv = r ? qkv1 : qkv0;
    unsigned short* agg      = r ? agg0 : agg1;
    const int* rp = rowptr + r * (N_NODES + 1);
    const int* ss = srcs + r * E_EDGES;

    int nid = blockIdx.x * 4 + (threadIdx.x >> 6);
    if (nid >= n) return;
    int lane = threadIdx.x & 63;
    int half = lane >> 5;                  // edge parity owned by this half-wave
    int g = lane & 31;                     // 4-channel group
    int c0 = g << 2;
    int h = g >> 2;
    int goff = 128 + (g << 3);

    const unsigned short* qrow = qd + (size_t)nid * 384 + c0;
    float q0 = bf2f(qrow[0]), q1 = bf2f(qrow[1]), q2 = bf2f(qrow[2]), q3 = bf2f(qrow[3]);
    float p = prel[r * 8 + h] * 0.25f;

    float mA = -1e30f, sA = 0.f, aA0 = 0.f, aA1 = 0.f, aA2 = 0.f, aA3 = 0.f;
    float mB = -1e30f, sB = 0.f, aB0 = 0.f, aB1 = 0.f, aB2 = 0.f, aB3 = 0.f;
    int beg = rp[nid], end = rp[nid + 1];
    int i0 = beg + half;
    if (i0 < end) {
        int e1 = end - 1;
        int cA = i0 < e1 ? i0 : e1;
        int cB = i0 + 2 < e1 ? i0 + 2 : e1;
        u16x8 kvA = *(const u16x8*)(sv + (size_t)ss[cA] * 384 + goff);
        u16x8 kvB = *(const u16x8*)(sv + (size_t)ss[cB] * 384 + goff);
        int nA = i0 + 4 < e1 ? i0 + 4 : e1;
        int nB = i0 + 6 < e1 ? i0 + 6 : e1;
        int idxAn = ss[nA];
        int idxBn = ss[nB];
        for (int i = i0; i < end; i += 4) {
            // gathers for edges i+4 / i+6 (indices already resident)
            u16x8 kvAn = *(const u16x8*)(sv + (size_t)idxAn * 384 + goff);
            u16x8 kvBn = *(const u16x8*)(sv + (size_t)idxBn * 384 + goff);
            // indices for edges i+8 / i+10
            int pA = i + 8 < e1 ? i + 8 : e1;
            int pB = i + 10 < e1 ? i + 10 : e1;
            int idxAnn = ss[pA];
            int idxBnn = ss[pB];
            // ---- stream A update (edge i, always valid here)
            {
                float sc = q0 * bf2f(kvA[0]) + q1 * bf2f(kvA[1]) + q2 * bf2f(kvA[2]) + q3 * bf2f(kvA[3]);
                sc += __shfl_xor(sc, 1);
                sc += __shfl_xor(sc, 2);
                float score = sc * p;
                float nm = fmaxf(mA, score);
                float rsc = __expf(mA - nm);
                float e = __expf(score - nm);
                sA = sA * rsc + e;
                aA0 = aA0 * rsc + e * bf2f(kvA[4]);
                aA1 = aA1 * rsc + e * bf2f(kvA[5]);
                aA2 = aA2 * rsc + e * bf2f(kvA[6]);
                aA3 = aA3 * rsc + e * bf2f(kvA[7]);
                mA = nm;
            }
            // ---- stream B update (edge i+2, may be past end)
            if (i + 2 < end) {
                float sc = q0 * bf2f(kvB[0]) + q1 * bf2f(kvB[1]) + q2 * bf2f(kvB[2]) + q3 * bf2f(kvB[3]);
                sc += __shfl_xor(sc, 1);
                sc += __shfl_xor(sc, 2);
                float score = sc * p;
                float nm = fmaxf(mB, score);
                float rsc = __expf(mB - nm);
                float e = __expf(score - nm);
                sB = sB * rsc + e;
                aB0 = aB0 * rsc + e * bf2f(kvB[4]);
                aB1 = aB1 * rsc + e * bf2f(kvB[5]);
                aB2 = aB2 * rsc + e * bf2f(kvB[6]);
                aB3 = aB3 * rsc + e * bf2f(kvB[7]);
                mB = nm;
            }
            kvA = kvAn; kvB = kvBn; idxAn = idxAnn; idxBn = idxBnn;
        }
        // ---- merge stream B into A (exact)
        float nm = fmaxf(mA, mB);
        float fA = __expf(mA - nm), fB = __expf(mB - nm);
        sA = sA * fA + sB * fB;
        aA0 = aA0 * fA + aB0 * fB;
        aA1 = aA1 * fA + aB1 * fB;
        aA2 = aA2 * fA + aB2 * fB;
        aA3 = aA3 * fA + aB3 * fB;
        mA = nm;
    }
    // ---- merge the two halves' states
    float mo = __shfl_xor(mA, 32);
    float nm2 = fmaxf(mA, mo);
    float f = __expf(mA - nm2);
    sA *= f; aA0 *= f; aA1 *= f; aA2 *= f; aA3 *= f;
    sA += __shfl_xor(sA, 32);
    aA0 += __shfl_xor(aA0, 32);
    aA1 += __shfl_xor(aA1, 32);
    aA2 += __shfl_xor(aA2, 32);
    aA3 += __shfl_xor(aA3, 32);

    if (half == 0) {
        float inv = 1.f / (sA + 1e-16f);
        ushort4 o;
        o.x = f2bf(gelu_f(aA0 * inv)); o.y = f2bf(gelu_f(aA1 * inv));
        o.z = f2bf(gelu_f(aA2 * inv)); o.w = f2bf(gelu_f(aA3 * inv));
        *(ushort4*)(agg + (size_t)nid * HID + c0) = o;
    }
}

// ============================ orchestration ============================
extern "C" void kernel_launch(void* const* d_in, const int* in_sizes, int n_in,
                              void* d_out, int out_size, void* d_ws, size_t ws_size,
                              hipStream_t stream)
{
    (void)in_sizes; (void)n_in; (void)out_size; (void)ws_size;
    const float* x_author = (const float*)d_in[0];
    const float* x_paper  = (const float*)d_in[1];
    const int*   e_writes = (const int*)d_in[2];
    const int*   e_rev    = (const int*)d_in[3];
    const float* W_in = (const float*)d_in[4];
    const float* b_in = (const float*)d_in[5];
    const float* Wq = (const float*)d_in[6];
    const float* bq = (const float*)d_in[7];
    const float* Wk = (const float*)d_in[8];
    const float* bk = (const float*)d_in[9];
    const float* Wv = (const float*)d_in[10];
    const float* bv = (const float*)d_in[11];
    const float* Wa = (const float*)d_in[12];
    const float* ba = (const float*)d_in[13];
    const float* skip = (const float*)d_in[14];
    const float* a_rel = (const float*)d_in[15];
    const float* m_rel = (const float*)d_in[16];
    const float* p_rel = (const float*)d_in[17];
    const float* W_out = (const float*)d_in[18];
    const float* b_out = (const float*)d_in[19];
    float* out = (float*)d_out;

    const size_t NC = (size_t)N_NODES * HID;       // 3.2M elems
    const size_t NQ = (size_t)N_NODES * 384;
    unsigned short* U = (unsigned short*)d_ws;
    unsigned short* cur0 = U;             unsigned short* cur1 = U + NC;
    unsigned short* agg0 = U + 2 * NC;    unsigned short* agg1 = U + 3 * NC;
    unsigned short* qkv0 = U + 4 * NC;    unsigned short* qkv1 = U + 4 * NC + NQ;
    unsigned short* WTin  = U + 4 * NC + 2 * NQ;            // 2*128*128
    unsigned short* WTqkv = WTin + 2 * 16384;               // 4*384*128
    unsigned short* WTa   = WTqkv + 4 * 49152;              // 4*128*128
    unsigned short* WTout = WTa + 4 * 16384;                // 64*128
    float* bfq = (float*)(WTout + OUTC * 128);              // 4*384 fp32
    int* I      = (int*)(bfq + 4 * 384);
    int* cnt    = I;
    int* part   = I + 2 * N_NODES;
    int* rowptr = part + 2 * NPB;
    int* srcs   = rowptr + 2 * (N_NODES + 1);

    dim3 blk(256);
    int eGrid = (E_EDGES + 255) / 256;
    int mmX = (N_NODES + 127) / 128;                        // 196
    int attnX = (N_NODES + 3) / 4;                          // 6250 (1 wave per node)
    int prepX = (384 * 129 + 255) / 256;                    // 194

    // ---- CSR ----
    hipMemsetAsync(cnt, 0, 2 * N_NODES * sizeof(int), stream);
    hist2<<<dim3(eGrid, 2), blk, 0, stream>>>(e_writes, e_rev, cnt);
    csr_partial<<<dim3(NPB, 2), blk, 0, stream>>>(cnt, part);
    csr_scanpart<<<1, 128, 0, stream>>>(part);
    csr_write<<<dim3(NPB, 2), blk, 0, stream>>>(cnt, part, rowptr);
    scatter2<<<dim3(eGrid, 2), blk, 0, stream>>>(e_writes, e_rev, cnt, srcs);

    // ---- weight prep ----
    tconv<<<dim3(64, 2), blk, 0, stream>>>(W_in, WTin, HID);
    tconv<<<dim3(64, 4), blk, 0, stream>>>(Wa, WTa, HID);
    tconv<<<dim3(32, 1), blk, 0, stream>>>(W_out, WTout, OUTC);
    prep_qkv<<<dim3(prepX, 4), blk, 0, stream>>>(Wq, bq, Wk, bk, Wv, bv, a_rel, m_rel, WTqkv, bfq);

    // ---- input projection + relu (fp32 A) ----
    mm4_kernel<HID, 128, 1, 1, 0><<<dim3(mmX, 1, 2), blk, 0, stream>>>(
        x_author, x_paper, WTin, WTin + 16384, b_in, b_in + HID,
        nullptr, nullptr, nullptr, cur0, cur1, N_NODES);

    for (int l = 0; l < 2; l++) {
        mm4_kernel<384, 128, 0, 0, 1><<<dim3(mmX, 3, 2), blk, 0, stream>>>(
            cur0, cur1,
            WTqkv + (size_t)(l * 2 + 0) * 49152, WTqkv + (size_t)(l * 2 + 1) * 49152,
            bfq + (l * 2 + 0) * 384, bfq + (l * 2 + 1) * 384,
            nullptr, nullptr, nullptr, qkv0, qkv1, N_NODES);
        attn5_kernel<<<dim3(attnX, 2), blk, 0, stream>>>(
            qkv0, qkv1, rowptr, srcs, p_rel + (size_t)l * 16, agg0, agg1, N_NODES);
        mm4_kernel<HID, 128, 2, 0, 0><<<dim3(mmX, 1, 2), blk, 0, stream>>>(
            agg0, agg1,
            WTa + (size_t)(l * 2 + 0) * 16384, WTa + (size_t)(l * 2 + 1) * 16384,
            ba + (l * 2 + 0) * HID, ba + (l * 2 + 1) * HID,
            cur0, cur1, skip + l * 2, cur0, cur1, N_NODES);
    }

    // ---- final projection (fp32 out) ----
    mm4_kernel<OUTC, 64, 3, 0, 0><<<dim3(mmX, 1, 2), blk, 0, stream>>>(
        cur0, cur1, WTout, WTout, b_out, b_out,
        nullptr, nullptr, nullptr, out, out + (size_t)N_NODES * OUTC, N_NODES);
}

// Round 12
// 360.176 us; speedup vs baseline: 1.0986x; 1.0332x over previous
//
#include <hip/hip_runtime.h>
#include <math.h>

#define N_NODES 25000
#define E_EDGES 250000
#define HID 128
#define OUTC 64
#define NPB 98          // ceil(25000/256)

using bf16x8 = __attribute__((ext_vector_type(8))) short;
using u16x8  = __attribute__((ext_vector_type(8))) unsigned short;
using f32x4  = __attribute__((ext_vector_type(4))) float;

__device__ __forceinline__ unsigned short f2bf(float f) {   // RNE float->bf16
    unsigned u = __float_as_uint(f);
    u = (u + 0x7fffu + ((u >> 16) & 1u)) >> 16;
    return (unsigned short)u;
}
__device__ __forceinline__ float bf2f(unsigned short h) {
    return __uint_as_float(((unsigned)h) << 16);
}
__device__ __forceinline__ float gelu_f(float x) {
    return 0.5f * x * (1.0f + erff(x * 0.70710678118654752440f));
}
__device__ __forceinline__ float ex2(float x) {             // native v_exp_f32 (2^x)
    return __builtin_amdgcn_exp2f(x);
}

// ============================ CSR build ============================
__global__ void hist2(const int* __restrict__ e0, const int* __restrict__ e1,
                      int* __restrict__ cnt) {
    int r = blockIdx.y;
    const int* d = (r ? e1 : e0) + E_EDGES;
    int e = blockIdx.x * 256 + threadIdx.x;
    if (e < E_EDGES) atomicAdd(&cnt[r * N_NODES + d[e]], 1);
}

__global__ void csr_partial(const int* __restrict__ cnt, int* __restrict__ part) {
    int r = blockIdx.y, b = blockIdx.x, t = threadIdx.x;
    int idx = b * 256 + t;
    int v = (idx < N_NODES) ? cnt[r * N_NODES + idx] : 0;
    #pragma unroll
    for (int d = 1; d < 64; d <<= 1) v += __shfl_xor(v, d);
    __shared__ int ws[4];
    if ((t & 63) == 0) ws[t >> 6] = v;
    __syncthreads();
    if (t == 0) part[r * NPB + b] = ws[0] + ws[1] + ws[2] + ws[3];
}

__global__ void csr_scanpart(int* __restrict__ part) {
    int w = threadIdx.x >> 6, lane = threadIdx.x & 63;
    int base = w * NPB;
    int a = part[base + lane];
    int b = (lane < NPB - 64) ? part[base + 64 + lane] : 0;
    int va = a, vb = b;
    #pragma unroll
    for (int d = 1; d < 64; d <<= 1) { int u = __shfl_up(va, d); if (lane >= d) va += u; }
    #pragma unroll
    for (int d = 1; d < 64; d <<= 1) { int u = __shfl_up(vb, d); if (lane >= d) vb += u; }
    int tot0 = __shfl(va, 63);
    part[base + lane] = va - a;
    if (lane < NPB - 64) part[base + 64 + lane] = vb - b + tot0;
}

__global__ void csr_write(int* __restrict__ cnt, const int* __restrict__ part,
                          int* __restrict__ rowptr) {
    int r = blockIdx.y, b = blockIdx.x, t = threadIdx.x;
    int idx = b * 256 + t;
    int v = (idx < N_NODES) ? cnt[r * N_NODES + idx] : 0;
    int lane = t & 63, w = t >> 6;
    int iv = v;
    #pragma unroll
    for (int d = 1; d < 64; d <<= 1) { int u = __shfl_up(iv, d); if (lane >= d) iv += u; }
    __shared__ int wtot[4];
    if (lane == 63) wtot[w] = iv;
    __syncthreads();
    int woff = part[r * NPB + b];
    #pragma unroll
    for (int i = 0; i < 4; i++) if (i < w) woff += wtot[i];
    int excl = woff + iv - v;
    if (idx < N_NODES) {
        rowptr[r * (N_NODES + 1) + idx] = excl;
        cnt[r * N_NODES + idx] = excl;
    }
    if (b == 0 && t == 0) rowptr[r * (N_NODES + 1) + N_NODES] = E_EDGES;
}

__global__ void scatter2(const int* __restrict__ e0, const int* __restrict__ e1,
                         int* __restrict__ cursor, int* __restrict__ srcs) {
    int r = blockIdx.y;
    const int* e = r ? e1 : e0;
    int i = blockIdx.x * 256 + threadIdx.x;
    if (i < E_EDGES) {
        int p = atomicAdd(&cursor[r * N_NODES + e[E_EDGES + i]], 1);
        srcs[r * E_EDGES + p] = e[i];
    }
}

// =============== fused weight transpose: W_in(2) + Wa(4) + W_out -> bf16 [C][128] ===============
__global__ void tconv_all(const float* __restrict__ W_in, const float* __restrict__ Wa,
                          const float* __restrict__ W_out,
                          unsigned short* __restrict__ WTin, unsigned short* __restrict__ WTa,
                          unsigned short* __restrict__ WTout) {
    int idx = blockIdx.x * 256 + threadIdx.x;
    if (idx < 32768) {                       // W_in: 2 x [128][128]
        int m = idx >> 14, rr = idx & 16383;
        int c = rr >> 7, k = rr & 127;
        WTin[idx] = f2bf(W_in[m * 16384 + k * 128 + c]);
    } else if (idx < 32768 + 65536) {        // Wa: 4 x [128][128]
        int j = idx - 32768;
        int m = j >> 14, rr = j & 16383;
        int c = rr >> 7, k = rr & 127;
        WTa[j] = f2bf(Wa[m * 16384 + k * 128 + c]);
    } else if (idx < 32768 + 65536 + 8192) { // W_out: [128][64]
        int j = idx - 98304;
        int c = j >> 7, k = j & 127;
        WTout[j] = f2bf(W_out[k * 64 + c]);
    }
}

// fused QKV' weights, transposed bf16 [p][384col][128k] + fp32 bias [p][384].
// Columns >=128 are PRE-PERMUTED into the attention's [k4|v4] interleave, so the
// matmul writes linearly (permutation free at prep time): output col 128+8g+w holds
// K channel 4g+w (w<4) or V channel 4g+(w-4) (w>=4).
__global__ __launch_bounds__(256) void prep_qkv(
    const float* __restrict__ Wq, const float* __restrict__ bq,
    const float* __restrict__ Wk, const float* __restrict__ bk,
    const float* __restrict__ Wv, const float* __restrict__ bv,
    const float* __restrict__ a_rel, const float* __restrict__ m_rel,
    unsigned short* __restrict__ WT, float* __restrict__ bfq)
{
    int p = blockIdx.y;                    // l*2+t (relation r == source type t)
    __shared__ float sA[2048], sM[2048];
    for (int i = threadIdx.x; i < 2048; i += 256) {
        sA[i] = a_rel[p * 2048 + i];
        sM[i] = m_rel[p * 2048 + i];
    }
    __syncthreads();
    int idx = blockIdx.x * 256 + threadIdx.x;
    if (idx >= 384 * 129) return;
    int c = idx / 129;
    int ik = idx - c * 129;                // 0..127 weight row, 128 = bias
    const float* wq = Wq + (size_t)p * 16384;
    const float* wk = Wk + (size_t)p * 16384;
    const float* wv = Wv + (size_t)p * 16384;
    float val;
    if (c < 128) {
        val = (ik < 128) ? wq[ik * 128 + c] : bq[p * 128 + c];
    } else {
        int u = c - 128;
        int gg = u >> 3, w = u & 7;
        int cc = (gg << 2) + (w & 3);      // source K/V channel
        int h = cc >> 4, f = cc & 15;
        const float* row;
        const float* tab;
        if (w < 4) {                       // K column
            row = (ik < 128) ? &wk[ik * 128 + h * 16] : &bk[p * 128 + h * 16];
            tab = &sA[h * 256];
        } else {                           // V column
            row = (ik < 128) ? &wv[ik * 128 + h * 16] : &bv[p * 128 + h * 16];
            tab = &sM[h * 256];
        }
        float s = 0.f;
        #pragma unroll
        for (int d = 0; d < 16; d++) s = fmaf(row[d], tab[d * 16 + f], s);
        val = s;
    }
    if (ik < 128) WT[(size_t)p * 384 * 128 + (size_t)c * 128 + ik] = f2bf(val);
    else bfq[p * 384 + c] = val;
}

// ============================ MFMA matmul (LDS-staged W) ============================
// C[z] = epilogue(A[z][nrows,128] @ WT[z]^T + b[z]);  WT bf16 [NOUT][128].
// OUTMODE: 0 bf16 store, 1 relu+bf16, 2 gated residual bf16 (in-place), 3 fp32 store.
template<int NOUT, int BN, int OUTMODE, int A_FP32>
__global__ __launch_bounds__(256) void mm4_kernel(
    const void* __restrict__ A0, const void* __restrict__ A1,
    const unsigned short* __restrict__ W0, const unsigned short* __restrict__ W1,
    const float* __restrict__ b0, const float* __restrict__ b1,
    const unsigned short* __restrict__ res0, const unsigned short* __restrict__ res1,
    const float* __restrict__ skipp,
    void* __restrict__ C0, void* __restrict__ C1, int nrows)
{
    constexpr int CF = BN / 16;
    __shared__ unsigned short sW[BN * 128];
    int z = blockIdx.z;
    const void* Av = z ? A1 : A0;
    const unsigned short* W = z ? W1 : W0;
    const float* bias = z ? b1 : b0;
    const unsigned short* res = z ? res1 : res0;
    void* Cv = z ? C1 : C0;

    int t = threadIdx.x;
    int w = t >> 6, lane = t & 63, lo = lane & 15, hi = lane >> 4;
    int col0 = blockIdx.y * BN;
    int rowbase = blockIdx.x * 128 + w * 32;

    // ---- stage swizzled W tile: sW[col*128 + (ch^(col&7))*8] = Wg[col*128 + ch*8]
    const unsigned short* Wg = W + (size_t)col0 * 128;
    #pragma unroll
    for (int it = 0; it < BN / 16; ++it) {            // BN*16 chunks / 256 threads
        int idx = it * 256 + t;
        int col = idx >> 4, ch = idx & 15;
        bf16x8 v = *(const bf16x8*)(Wg + (size_t)col * 128 + ch * 8);
        *(bf16x8*)&sW[col * 128 + ((ch ^ (col & 7)) << 3)] = v;
    }

    // ---- A fragments (2 row-frags x 4 k-frags), loads overlap the staging
    bf16x8 a[2][4];
    #pragma unroll
    for (int rf = 0; rf < 2; rf++) {
        int r = rowbase + rf * 16 + lo;
        if (r > nrows - 1) r = nrows - 1;
        if (A_FP32) {
            const float* Arow = (const float*)Av + (size_t)r * HID;
            #pragma unroll
            for (int kk = 0; kk < 4; kk++) {
                float4 x0 = *(const float4*)(Arow + kk * 32 + hi * 8);
                float4 x1 = *(const float4*)(Arow + kk * 32 + hi * 8 + 4);
                bf16x8 v;
                v[0] = (short)f2bf(x0.x); v[1] = (short)f2bf(x0.y);
                v[2] = (short)f2bf(x0.z); v[3] = (short)f2bf(x0.w);
                v[4] = (short)f2bf(x1.x); v[5] = (short)f2bf(x1.y);
                v[6] = (short)f2bf(x1.z); v[7] = (short)f2bf(x1.w);
                a[rf][kk] = v;
            }
        } else {
            const unsigned short* Arow = (const unsigned short*)Av + (size_t)r * HID;
            #pragma unroll
            for (int kk = 0; kk < 4; kk++)
                a[rf][kk] = *(const bf16x8*)(Arow + kk * 32 + hi * 8);
        }
    }
    __syncthreads();

    f32x4 acc[2][CF];
    #pragma unroll
    for (int rf = 0; rf < 2; rf++)
        #pragma unroll
        for (int cf = 0; cf < CF; cf++) acc[rf][cf] = (f32x4){0.f, 0.f, 0.f, 0.f};

    #pragma unroll
    for (int cf = 0; cf < CF; cf++) {
        int colb = cf * 16 + lo;
        int sbase = colb * 128;
        int sx = colb & 7;
        bf16x8 bfr[4];
        #pragma unroll
        for (int kk = 0; kk < 4; kk++) {
            int ch = kk * 4 + hi;
            bfr[kk] = *(const bf16x8*)&sW[sbase + ((ch ^ sx) << 3)];
        }
        #pragma unroll
        for (int kk = 0; kk < 4; kk++) {
            acc[0][cf] = __builtin_amdgcn_mfma_f32_16x16x32_bf16(a[0][kk], bfr[kk], acc[0][cf], 0, 0, 0);
            acc[1][cf] = __builtin_amdgcn_mfma_f32_16x16x32_bf16(a[1][kk], bfr[kk], acc[1][cf], 0, 0, 0);
        }
    }

    float beta = 0.f, omb = 0.f;
    if (OUTMODE == 2) { float sv = skipp[z]; beta = 1.f / (1.f + __expf(-sv)); omb = 1.f - beta; }
    #pragma unroll
    for (int rf = 0; rf < 2; rf++) {
        #pragma unroll
        for (int cf = 0; cf < CF; cf++) {
            int col = col0 + cf * 16 + lo;
            float bb = bias[col];
            #pragma unroll
            for (int j = 0; j < 4; j++) {
                int r = rowbase + rf * 16 + hi * 4 + j;
                if (r >= nrows) continue;
                float v = acc[rf][cf][j] + bb;
                if (OUTMODE == 1) v = fmaxf(v, 0.f);
                if (OUTMODE == 2) v = beta * v + omb * bf2f(res[(size_t)r * NOUT + col]);
                if (OUTMODE == 3) ((float*)Cv)[(size_t)r * NOUT + col] = v;
                else ((unsigned short*)Cv)[(size_t)r * NOUT + col] = f2bf(v);
            }
        }
    }
}

// ==================== attention: one wave per node, 4 streams, defer-max, exp2 ====================
// Half-waves take edge parities; each half runs TWO interleaved streams (stride 4).
// Defer-max (T13): rescale only when score exceeds m+8 (exp2 domain; e<=256), so the
// common path is 1 exp2 + fma accumulate. All softmax math in exp2 domain (log2e folded into p).
__global__ __launch_bounds__(256) void attn6_kernel(
    const unsigned short* __restrict__ qkv0, const unsigned short* __restrict__ qkv1,
    const int* __restrict__ rowptr, const int* __restrict__ srcs,
    const float* __restrict__ prel,
    unsigned short* __restrict__ agg0, unsigned short* __restrict__ agg1, int n)
{
    int r = blockIdx.y;                    // relation; src type = r, dst type = 1-r
    const unsigned short* qd = r ? qkv0 : qkv1;
    const unsigned short* sv = r ? qkv1 : qkv0;
    unsigned short* agg      = r ? agg0 : agg1;
    const int* rp = rowptr + r * (N_NODES + 1);
    const int* ss = srcs + r * E_EDGES;

    int nid = blockIdx.x * 4 + (threadIdx.x >> 6);
    if (nid >= n) return;
    int lane = threadIdx.x & 63;
    int half = lane >> 5;                  // edge parity owned by this half-wave
    int g = lane & 31;                     // 4-channel group
    int c0 = g << 2;
    int h = g >> 2;
    int goff = 128 + (g << 3);

    const unsigned short* qrow = qd + (size_t)nid * 384 + c0;
    float q0 = bf2f(qrow[0]), q1 = bf2f(qrow[1]), q2 = bf2f(qrow[2]), q3 = bf2f(qrow[3]);
    float p2 = prel[r * 8 + h] * 0.25f * 1.44269504088896f;   // p/sqrt(D) * log2(e)

    float mA = -1e30f, sA = 0.f, aA0 = 0.f, aA1 = 0.f, aA2 = 0.f, aA3 = 0.f;
    float mB = -1e30f, sB = 0.f, aB0 = 0.f, aB1 = 0.f, aB2 = 0.f, aB3 = 0.f;
    int beg = rp[nid], end = rp[nid + 1];
    int i0 = beg + half;
    if (i0 < end) {
        int e1 = end - 1;
        int cA = i0 < e1 ? i0 : e1;
        int cB = i0 + 2 < e1 ? i0 + 2 : e1;
        u16x8 kvA = *(const u16x8*)(sv + (size_t)ss[cA] * 384 + goff);
        u16x8 kvB = *(const u16x8*)(sv + (size_t)ss[cB] * 384 + goff);
        int nA = i0 + 4 < e1 ? i0 + 4 : e1;
        int nB = i0 + 6 < e1 ? i0 + 6 : e1;
        int idxAn = ss[nA];
        int idxBn = ss[nB];
        for (int i = i0; i < end; i += 4) {
            // gathers for edges i+4 / i+6 (indices already resident)
            u16x8 kvAn = *(const u16x8*)(sv + (size_t)idxAn * 384 + goff);
            u16x8 kvBn = *(const u16x8*)(sv + (size_t)idxBn * 384 + goff);
            // indices for edges i+8 / i+10
            int pA = i + 8 < e1 ? i + 8 : e1;
            int pB = i + 10 < e1 ? i + 10 : e1;
            int idxAnn = ss[pA];
            int idxBnn = ss[pB];
            // ---- stream A update (edge i, always valid here)
            {
                float sc = q0 * bf2f(kvA[0]) + q1 * bf2f(kvA[1]) + q2 * bf2f(kvA[2]) + q3 * bf2f(kvA[3]);
                sc += __shfl_xor(sc, 1);
                sc += __shfl_xor(sc, 2);
                float sc2 = sc * p2;
                if (sc2 > mA + 8.f) {      // rare rescale
                    float rsc = ex2(mA - sc2);
                    sA *= rsc; aA0 *= rsc; aA1 *= rsc; aA2 *= rsc; aA3 *= rsc;
                    mA = sc2;
                }
                float e = ex2(sc2 - mA);
                sA += e;
                aA0 = fmaf(e, bf2f(kvA[4]), aA0);
                aA1 = fmaf(e, bf2f(kvA[5]), aA1);
                aA2 = fmaf(e, bf2f(kvA[6]), aA2);
                aA3 = fmaf(e, bf2f(kvA[7]), aA3);
            }
            // ---- stream B update (edge i+2, may be past end)
            if (i + 2 < end) {
                float sc = q0 * bf2f(kvB[0]) + q1 * bf2f(kvB[1]) + q2 * bf2f(kvB[2]) + q3 * bf2f(kvB[3]);
                sc += __shfl_xor(sc, 1);
                sc += __shfl_xor(sc, 2);
                float sc2 = sc * p2;
                if (sc2 > mB + 8.f) {
                    float rsc = ex2(mB - sc2);
                    sB *= rsc; aB0 *= rsc; aB1 *= rsc; aB2 *= rsc; aB3 *= rsc;
                    mB = sc2;
                }
                float e = ex2(sc2 - mB);
                sB += e;
                aB0 = fmaf(e, bf2f(kvB[4]), aB0);
                aB1 = fmaf(e, bf2f(kvB[5]), aB1);
                aB2 = fmaf(e, bf2f(kvB[6]), aB2);
                aB3 = fmaf(e, bf2f(kvB[7]), aB3);
            }
            kvA = kvAn; kvB = kvBn; idxAn = idxAnn; idxBn = idxBnn;
        }
        // ---- merge stream B into A (exact, exp2 domain)
        float nm = fmaxf(mA, mB);
        float fA = ex2(mA - nm), fB = ex2(mB - nm);
        sA = sA * fA + sB * fB;
        aA0 = aA0 * fA + aB0 * fB;
        aA1 = aA1 * fA + aB1 * fB;
        aA2 = aA2 * fA + aB2 * fB;
        aA3 = aA3 * fA + aB3 * fB;
        mA = nm;
    }
    // ---- merge the two halves' states
    float mo = __shfl_xor(mA, 32);
    float nm2 = fmaxf(mA, mo);
    float f = ex2(mA - nm2);
    sA *= f; aA0 *= f; aA1 *= f; aA2 *= f; aA3 *= f;
    sA += __shfl_xor(sA, 32);
    aA0 += __shfl_xor(aA0, 32);
    aA1 += __shfl_xor(aA1, 32);
    aA2 += __shfl_xor(aA2, 32);
    aA3 += __shfl_xor(aA3, 32);

    if (half == 0) {
        float inv = 1.f / (sA + 1e-16f);
        ushort4 o;
        o.x = f2bf(gelu_f(aA0 * inv)); o.y = f2bf(gelu_f(aA1 * inv));
        o.z = f2bf(gelu_f(aA2 * inv)); o.w = f2bf(gelu_f(aA3 * inv));
        *(ushort4*)(agg + (size_t)nid * HID + c0) = o;
    }
}

// ============================ orchestration ============================
extern "C" void kernel_launch(void* const* d_in, const int* in_sizes, int n_in,
                              void* d_out, int out_size, void* d_ws, size_t ws_size,
                              hipStream_t stream)
{
    (void)in_sizes; (void)n_in; (void)out_size; (void)ws_size;
    const float* x_author = (const float*)d_in[0];
    const float* x_paper  = (const float*)d_in[1];
    const int*   e_writes = (const int*)d_in[2];
    const int*   e_rev    = (const int*)d_in[3];
    const float* W_in = (const float*)d_in[4];
    const float* b_in = (const float*)d_in[5];
    const float* Wq = (const float*)d_in[6];
    const float* bq = (const float*)d_in[7];
    const float* Wk = (const float*)d_in[8];
    const float* bk = (const float*)d_in[9];
    const float* Wv = (const float*)d_in[10];
    const float* bv = (const float*)d_in[11];
    const float* Wa = (const float*)d_in[12];
    const float* ba = (const float*)d_in[13];
    const float* skip = (const float*)d_in[14];
    const float* a_rel = (const float*)d_in[15];
    const float* m_rel = (const float*)d_in[16];
    const float* p_rel = (const float*)d_in[17];
    const float* W_out = (const float*)d_in[18];
    const float* b_out = (const float*)d_in[19];
    float* out = (float*)d_out;

    const size_t NC = (size_t)N_NODES * HID;       // 3.2M elems
    const size_t NQ = (size_t)N_NODES * 384;
    unsigned short* U = (unsigned short*)d_ws;
    unsigned short* cur0 = U;             unsigned short* cur1 = U + NC;
    unsigned short* agg0 = U + 2 * NC;    unsigned short* agg1 = U + 3 * NC;
    unsigned short* qkv0 = U + 4 * NC;    unsigned short* qkv1 = U + 4 * NC + NQ;
    unsigned short* WTin  = U + 4 * NC + 2 * NQ;            // 2*128*128
    unsigned short* WTqkv = WTin + 2 * 16384;               // 4*384*128
    unsigned short* WTa   = WTqkv + 4 * 49152;              // 4*128*128
    unsigned short* WTout = WTa + 4 * 16384;                // 64*128
    float* bfq = (float*)(WTout + OUTC * 128);              // 4*384 fp32
    int* I      = (int*)(bfq + 4 * 384);
    int* cnt    = I;
    int* part   = I + 2 * N_NODES;
    int* rowptr = part + 2 * NPB;
    int* srcs   = rowptr + 2 * (N_NODES + 1);

    dim3 blk(256);
    int eGrid = (E_EDGES + 255) / 256;
    int mmX = (N_NODES + 127) / 128;                        // 196
    int attnX = (N_NODES + 3) / 4;                          // 6250 (1 wave per node)
    int prepX = (384 * 129 + 255) / 256;                    // 194
    int tcX = (32768 + 65536 + 8192 + 255) / 256;           // 416

    // ---- CSR ----
    (void)hipMemsetAsync(cnt, 0, 2 * N_NODES * sizeof(int), stream);
    hist2<<<dim3(eGrid, 2), blk, 0, stream>>>(e_writes, e_rev, cnt);
    csr_partial<<<dim3(NPB, 2), blk, 0, stream>>>(cnt, part);
    csr_scanpart<<<1, 128, 0, stream>>>(part);
    csr_write<<<dim3(NPB, 2), blk, 0, stream>>>(cnt, part, rowptr);
    scatter2<<<dim3(eGrid, 2), blk, 0, stream>>>(e_writes, e_rev, cnt, srcs);

    // ---- weight prep (fused transposes + fused-permuted QKV) ----
    tconv_all<<<tcX, blk, 0, stream>>>(W_in, Wa, W_out, WTin, WTa, WTout);
    prep_qkv<<<dim3(prepX, 4), blk, 0, stream>>>(Wq, bq, Wk, bk, Wv, bv, a_rel, m_rel, WTqkv, bfq);

    // ---- input projection + relu (fp32 A) ----
    mm4_kernel<HID, 128, 1, 1><<<dim3(mmX, 1, 2), blk, 0, stream>>>(
        x_author, x_paper, WTin, WTin + 16384, b_in, b_in + HID,
        nullptr, nullptr, nullptr, cur0, cur1, N_NODES);

    for (int l = 0; l < 2; l++) {
        mm4_kernel<384, 128, 0, 0><<<dim3(mmX, 3, 2), blk, 0, stream>>>(
            cur0, cur1,
            WTqkv + (size_t)(l * 2 + 0) * 49152, WTqkv + (size_t)(l * 2 + 1) * 49152,
            bfq + (l * 2 + 0) * 384, bfq + (l * 2 + 1) * 384,
            nullptr, nullptr, nullptr, qkv0, qkv1, N_NODES);
        attn6_kernel<<<dim3(attnX, 2), blk, 0, stream>>>(
            qkv0, qkv1, rowptr, srcs, p_rel + (size_t)l * 16, agg0, agg1, N_NODES);
        mm4_kernel<HID, 128, 2, 0><<<dim3(mmX, 1, 2), blk, 0, stream>>>(
            agg0, agg1,
            WTa + (size_t)(l * 2 + 0) * 16384, WTa + (size_t)(l * 2 + 1) * 16384,
            ba + (l * 2 + 0) * HID, ba + (l * 2 + 1) * HID,
            cur0, cur1, skip + l * 2, cur0, cur1, N_NODES);
    }

    // ---- final projection (fp32 out) ----
    mm4_kernel<OUTC, 64, 3, 0><<<dim3(mmX, 1, 2), blk, 0, stream>>>(
        cur0, cur1, WTout, WTout, b_out, b_out,
        nullptr, nullptr, nullptr, out, out + (size_t)N_NODES * OUTC, N_NODES);
}